// Round 14
// baseline (251.359 us; speedup 1.0000x reference)
//
#include <hip/hip_runtime.h>
#include <hip/hip_bf16.h>

// clusterLayer: q = rownorm( 1 / (1 + ||x||^2 + ||c||^2 - 2 x.cT) )
// N=524288, K=256, D=256. fp32 in/out.
// r14: NT=2 cross-tile pipeline + simplified augmentation.
//   - Clusters in ws: -2*bf16(c), 17 frags/nj; frag16 = limbs3(1+|c|^2)
//     at k=256..258 (A-side only). Context aug frag is a CONSTANT
//     [1,1,1,0,...] -> no aug barrier, no wave-0 writer.
//   - Swapped MFMA: acc = 1 + c2 - 2xc after aug step; x2 folded as a
//     per-lane scalar add in pass 1 (lane = context row).
//   - Each block: 2 M-tiles of 64 rows. Tile-1 A-loads issued 2-at-a-time
//     at ks=0,4,8,12 inside tile-0's K-loop -> HBM in-flight window spans
//     the loop (fix for the ~50% HBM duty ceiling of r7-r13).
//   - 512 thr = 8 waves = 8 col-eighths x 2 row-halves; LDS 72 KiB,
//     launch_bounds(512,4): 2 blocks/CU, reg cap 128 (~114 used).

#define DD 256
#define KC 256
#define BM 64
#define NT 2

typedef __attribute__((ext_vector_type(4)))  float f32x4;
typedef __attribute__((ext_vector_type(16))) float f32x16;
typedef __attribute__((ext_vector_type(8)))  short bf16x8;
typedef __attribute__((ext_vector_type(4)))  short bf16x4;
typedef __attribute__((ext_vector_type(4)))  unsigned u32x4;

__device__ __forceinline__ short f2bf(float f) {
    union { float f; unsigned u; } v; v.f = f;
    unsigned r = (v.u + 0x7fffu + ((v.u >> 16) & 1u)) >> 16;
    return (short)r;
}

__device__ __forceinline__ float bf2f(short h) {
    return __builtin_bit_cast(float, ((unsigned)(unsigned short)h) << 16);
}

__device__ __forceinline__ unsigned cvtpk(float a, float b) {
    unsigned r;
    asm("v_cvt_pk_bf16_f32 %0, %1, %2" : "=v"(r) : "v"(a), "v"(b));
    return r;
}

__device__ __forceinline__ float frcp(float x) {
    return __builtin_amdgcn_rcpf(x);
}

template<int CTRL>
__device__ __forceinline__ float dpp_add(float v) {
    int iv = __builtin_bit_cast(int, v);
    int mv = __builtin_amdgcn_update_dpp(0, iv, CTRL, 0xf, 0xf, false);
    return v + __builtin_bit_cast(float, mv);
}
#define QUAD_SWAP1 0xB1    // quad_perm [1,0,3,2]

__device__ __forceinline__ f32x4 ld4(const float* p) { return *(const f32x4*)p; }

// ---------------- Kernel 0: prep clusters ----------------
// Main frags (nj*17+ks): -2*bf16(c) in 32x32x16 A-operand order.
// Aug frag (nj*17+16): lane l31 (k=256..263 side) = [c2h,c2m,c2l,0,0,0,0,0]
// with limbs3(1+|c|^2); k=264..271 side zeros.
__global__ __launch_bounds__(64)
void prep_clusters(const float* __restrict__ clus, short* __restrict__ wsb) {
    const int c = blockIdx.x;      // cluster row 0..255
    const int t = threadIdx.x;     // 0..63, 4 floats each
    f32x4 v = *(const f32x4*)(clus + c * DD + t * 4);
    bf16x4 o;
    o[0] = f2bf(-2.f * v[0]); o[1] = f2bf(-2.f * v[1]);
    o[2] = f2bf(-2.f * v[2]); o[3] = f2bf(-2.f * v[3]);

    const int j    = t >> 1;       // 8-elem chunk index within row (k/8)
    const int ks   = j >> 1;
    const int hi   = j & 1;
    const int half = t & 1;
    const int nj   = c >> 5;
    const int l31  = c & 31;
    *(bf16x4*)&wsb[(((nj * 17 + ks) * 64 + hi * 32 + l31) << 3) + half * 4] = o;

    float s = v[0]*v[0] + v[1]*v[1] + v[2]*v[2] + v[3]*v[3];   // raw |c|^2
    s += __shfl_xor(s, 1);  s += __shfl_xor(s, 2);  s += __shfl_xor(s, 4);
    s += __shfl_xor(s, 8);  s += __shfl_xor(s, 16); s += __shfl_xor(s, 32);
    if (t == 0) {
        float e = 1.f + s;
        short h = f2bf(e);  float e1 = e - bf2f(h);
        short m = f2bf(e1); float e2 = e1 - bf2f(m);
        short l = f2bf(e2);
        u32x4 a;
        a[0] = (unsigned)(unsigned short)h | ((unsigned)(unsigned short)m << 16);
        a[1] = (unsigned)(unsigned short)l;
        a[2] = 0u; a[3] = 0u;
        *(u32x4*)&wsb[((nj * 17 + 16) * 64 + l31) * 8] = a;         // k 256..263
        u32x4 z = {0u, 0u, 0u, 0u};
        *(u32x4*)&wsb[((nj * 17 + 16) * 64 + 32 + l31) * 8] = z;    // k 264..271
    }
}

// convert 8 f32x4 (64 rows' k-slice for this lane) -> bf16 frags + x2 partials
__device__ __forceinline__ void convert_tile(const f32x4* u, short* AfB,
                                             float (*x2p)[64], int w, int lane) {
    const int r0   = lane >> 1;
    const int half = lane & 1;
#pragma unroll
    for (int m = 0; m < 2; ++m) {
        float xs = 0.f;
#pragma unroll
        for (int c = 0; c < 2; ++c) {
            f32x4 a0 = u[m * 4 + 2 * c], a1 = u[m * 4 + 2 * c + 1];
            u32x4 o;
            o[0] = cvtpk(a0[0], a0[1]);
            o[1] = cvtpk(a0[2], a0[3]);
            o[2] = cvtpk(a1[0], a1[1]);
            o[3] = cvtpk(a1[2], a1[3]);
            xs += a0[0]*a0[0] + a0[1]*a0[1] + a0[2]*a0[2] + a0[3]*a0[3]
                + a1[0]*a1[0] + a1[1]*a1[1] + a1[2]*a1[2] + a1[3]*a1[3];
            const int j = w * 4 + half * 2 + c;          // k/8 chunk index
            *(u32x4*)&AfB[(j * 64 + m * 32 + r0) * 8] = o;
        }
        xs = dpp_add<QUAD_SWAP1>(xs);                    // combine halves
        if (half == 0) x2p[w][m * 32 + r0] = xs;
    }
}

// ---------------- Main kernel ----------------
__global__ __launch_bounds__(512, 4)
void cluster_q_main(const float* __restrict__ ctx,
                    const short* __restrict__ wsb,
                    float* __restrict__ out) {
    __shared__ short Af[NT][32 * 64 * 8];   // 2 x 32 KiB context frag buffers
    __shared__ float x2p8[NT][8][64];       // per-(buf,wave,row) |x|^2 partials
    __shared__ float rowsum2[8][2][64];     // per-(wave,hi,row) q half-sums

    const int t    = threadIdx.x;
    const int lane = t & 63;
    const int w    = t >> 6;             // wave = col-eighth 0..7
    const int l31  = lane & 31;
    const int hi   = lane >> 5;
    const size_t row_blk = (size_t)blockIdx.x * (BM * NT);

    const int r0   = lane >> 1;
    const int half = lane & 1;
    const float* src0 = ctx + (row_blk + (size_t)r0) * DD + w * 32 + half * 16;

    f32x4 u[8];

    // ---- prologue: load + convert tile 0 ----
#pragma unroll
    for (int jj = 0; jj < 8; ++jj)
        u[jj] = ld4(src0 + (size_t)((jj >> 2) * 32) * DD + (jj & 3) * 4);
    convert_tile(u, &Af[0][0], x2p8[0], w, lane);
    __syncthreads();

    // cluster fragment base: this wave's col-tile nj = w (17 frags)
    const short* bl = wsb + (size_t)(w * 17) * 512 + lane * 8;

    // constant context aug fragment: [1,1,1,0,...] on the k=256..263 side
    bf16x8 ctx_aug = (bf16x8)0;
    if (hi == 0) {
        ctx_aug[0] = (short)0x3F80; ctx_aug[1] = (short)0x3F80;
        ctx_aug[2] = (short)0x3F80;
    }

#pragma unroll
    for (int tile = 0; tile < NT; ++tile) {
        const size_t trow = row_blk + (size_t)tile * BM;

        // per-lane |x|^2 totals (lane = context row)
        float x2A = 0.f, x2B = 0.f;
#pragma unroll
        for (int q = 0; q < 8; ++q) {
            x2A += x2p8[tile][q][l31];
            x2B += x2p8[tile][q][32 + l31];
        }

        f32x16 acc0 = (f32x16)0.f, acc1 = (f32x16)0.f;

        // clusters: 3-slot rotation, distance 2; aug frag loaded upfront
        bf16x8 bs[3];
        bs[0] = *(const bf16x8*)(bl + 0 * 512);
        bs[1] = *(const bf16x8*)(bl + 1 * 512);
        bf16x8 bsa = *(const bf16x8*)(bl + 16 * 512);

        // context frags: ping-pong from LDS
        const short* AfC = &Af[tile][0];
        bf16x8 afA0 = *(const bf16x8*)&AfC[((0 + hi) * 64 +  0 + l31) * 8];
        bf16x8 afA1 = *(const bf16x8*)&AfC[((0 + hi) * 64 + 32 + l31) * 8];
        bf16x8 afB0, afB1;

#pragma unroll
        for (int ks = 0; ks < 16; ++ks) {
            const int cur = ks % 3;
            const bool even = (ks & 1) == 0;

            if (ks < 14)
                bs[(ks + 2) % 3] = *(const bf16x8*)(bl + (ks + 2) * 512);
            if (ks < 15) {
                const int jn = (ks + 1) * 2 + hi;
                bf16x8 v0 = *(const bf16x8*)&AfC[(jn * 64 +  0 + l31) * 8];
                bf16x8 v1 = *(const bf16x8*)&AfC[(jn * 64 + 32 + l31) * 8];
                if (even) { afB0 = v0; afB1 = v1; }
                else      { afA0 = v0; afA1 = v1; }
            }
            // staggered next-tile A loads: 2 per 4 K-steps (HBM window
            // spans the whole K-loop)
            if (tile + 1 < NT && (ks & 3) == 0) {
                const int j0 = (ks >> 2) * 2;
#pragma unroll
                for (int jj = 0; jj < 2; ++jj) {
                    const int jx = j0 + jj;
                    u[jx] = ld4(src0 + (size_t)(BM + (jx >> 2) * 32) * DD
                                     + (jx & 3) * 4);
                }
            }

            const bf16x8 a0 = even ? afA0 : afB0;
            const bf16x8 a1 = even ? afA1 : afB1;
            acc0 = __builtin_amdgcn_mfma_f32_32x32x16_bf16(bs[cur], a0, acc0, 0, 0, 0);
            acc1 = __builtin_amdgcn_mfma_f32_32x32x16_bf16(bs[cur], a1, acc1, 0, 0, 0);
        }

        // aug step: adds (1 + |c|^2) per cluster -> acc = 1 + c2 - 2xc
        acc0 = __builtin_amdgcn_mfma_f32_32x32x16_bf16(bsa, ctx_aug, acc0, 0, 0, 0);
        acc1 = __builtin_amdgcn_mfma_f32_32x32x16_bf16(bsa, ctx_aug, acc1, 0, 0, 0);

        // ---- pass 1: q = rcp(acc + x2lane), in-lane half-row sums ----
        float s0 = 0.f, s1 = 0.f;
#pragma unroll
        for (int r = 0; r < 16; ++r) {
            acc0[r] = frcp(acc0[r] + x2A); s0 += acc0[r];
            acc1[r] = frcp(acc1[r] + x2B); s1 += acc1[r];
        }
        rowsum2[w][hi][l31]      = s0;
        rowsum2[w][hi][32 + l31] = s1;
        __syncthreads();

        // ---- pass 2: row totals, normalize, dwordx4 stores ----
        float t0 = 0.f, t1 = 0.f;
#pragma unroll
        for (int q = 0; q < 8; ++q) {
            t0 += rowsum2[q][0][l31]      + rowsum2[q][1][l31];
            t1 += rowsum2[q][0][32 + l31] + rowsum2[q][1][32 + l31];
        }
        const float inv0 = frcp(t0);
        const float inv1 = frcp(t1);

        float* op0 = out + (trow + (size_t)l31) * KC        + w * 32 + 4 * hi;
        float* op1 = out + (trow + (size_t)(32 + l31)) * KC + w * 32 + 4 * hi;
#pragma unroll
        for (int i = 0; i < 4; ++i) {
            f32x4 v0, v1;
#pragma unroll
            for (int j = 0; j < 4; ++j) {
                v0[j] = acc0[4 * i + j] * inv0;   // cluster col = 8i + 4hi + j
                v1[j] = acc1[4 * i + j] * inv1;
            }
            *(f32x4*)(op0 + 8 * i) = v0;
            *(f32x4*)(op1 + 8 * i) = v1;
        }

        // ---- convert next tile into the other Af buffer ----
        if (tile + 1 < NT) {
            convert_tile(u, &Af[tile + 1][0], x2p8[tile + 1], w, lane);
            __syncthreads();   // Af ready; also WAR-guards rowsum2
        }
    }
}

extern "C" void kernel_launch(void* const* d_in, const int* in_sizes, int n_in,
                              void* d_out, int out_size, void* d_ws, size_t ws_size,
                              hipStream_t stream) {
    const float* ctx  = (const float*)d_in[0];
    const float* clus = (const float*)d_in[1];
    float* out = (float*)d_out;

    short* wsb = (short*)d_ws;     // cluster fragment image (8*17 KiB = 136 KiB)

    const int nrows = in_sizes[0] / DD;                      // 524288
    const int grid  = nrows / (BM * NT);                     // 4096

    hipLaunchKernelGGL(prep_clusters, dim3(KC), dim3(64), 0, stream, clus, wsb);
    hipLaunchKernelGGL(cluster_q_main, dim3(grid), dim3(512), 0, stream,
                       ctx, wsb, out);
}